// Round 19
// baseline (3377.813 us; speedup 1.0000x reference)
//
#include <hip/hip_runtime.h>
#include <hip/hip_bf16.h>
#include <math.h>

typedef __attribute__((ext_vector_type(4))) float vf4;
typedef __attribute__((ext_vector_type(8))) short vbf8;
typedef __attribute__((ext_vector_type(8))) unsigned short vus8;

#define NWG   64
#define NTHR  512
#define LEN   1024
#define H3    3072
#define CND   80
#define EMBD  128

// ---- ws byte offsets ----
#define TAB1_B  0ull
#define TAB2_B  (TAB1_B + 786432ull*4)
#define TAB3_B  (TAB2_B + 786432ull*4)
#define BF_B    (TAB3_B + 786432ull*4)            // bfrag: 128oct*2which*35frag*512 bf16
#define MELA_B  (BF_B   + 4587520ull*2)           // melA : 1024t*2m*3frag*512 bf16
#define AF_B    (MELA_B + 3145728ull*2)           // Afrag: 1025t*64frag*512 bf16
#define CNT_B   (AF_B   + 33587200ull*2)          // (unused)
#define W1F_B   (CNT_B + 4096ull)                 // O1w frags
#define W2F_B   (W1F_B + 1179648ull)
#define W3F_B   (W2F_B + 393216ull)
#define W4F_B   (W3F_B + 131072ull)
#define FOFS    8388608ull                        // flogits offset in d_out

// ============================ prep kernels (verbatim) ============================

__global__ __launch_bounds__(256) void make_tables(const float* __restrict__ IW,
                                                   const float* __restrict__ Ib,
                                                   const float* __restrict__ cemb,
                                                   const float* __restrict__ femb,
                                                   float* __restrict__ tab1,
                                                   float* __restrict__ tab2,
                                                   float* __restrict__ tab3) {
    int blk = blockIdx.x;
    int table = blk / 3072;
    int rem = blk % 3072;
    int row = rem / 12;
    int cc = rem % 12;
    int col = cc * 256 + threadIdx.x;
    int ofs = CND + table * EMBD;
    const float* emb = (table == 1) ? femb : cemb;
    float acc = 0.f;
    for (int k = 0; k < EMBD; ++k)
        acc += emb[row * EMBD + k] * IW[(size_t)(ofs + k) * H3 + col];
    if (table == 0) acc += Ib[col];
    if (table == 2 && ((col & 1023) < 768)) acc = 0.f;
    float* dst = (table == 0) ? tab1 : (table == 1 ? tab2 : tab3);
    dst[(size_t)row * H3 + col] = acc;
}

__global__ __launch_bounds__(256) void build_bfrag2(const float* __restrict__ Rw,
                                                    const float* __restrict__ IW,
                                                    const float* __restrict__ Rb,
                                                    unsigned short* __restrict__ Bf) {
    int idx = blockIdx.x * 256 + threadIdx.x;     // k*3072 + col, k in 0..1119
    int col = idx % 3072;
    int k   = idx / 3072;
    float v;
    if (k < 1024)       v = Rw[(size_t)k * H3 + col];
    else if (k < 1104)  v = IW[(size_t)(k - 1024) * H3 + col];
    else if (k == 1104) v = Rb[col];
    else return;

    int g  = col >> 10;
    int j  = col & 1023;
    int oct = j >> 3, jo = j & 7;
    int which, c;
    if (g < 2)      { which = 0; c = g * 8 + jo; }
    else {
        which = 1;
        if (k < 1024 || k == 1104) c = jo;
        else                        c = 8 + jo;
    }
    int kk = k >> 5, r5 = k & 31;
    int lane = (r5 >> 3) * 16 + c;
    int elem = r5 & 7;
    size_t dst = (((size_t)oct * 2 + which) * 35 + kk) * 512 + lane * 8 + elem;
    __hip_bfloat16 hb = __float2bfloat16(v);
    Bf[dst] = *(unsigned short*)&hb;
}

__global__ __launch_bounds__(256) void build_melA(const float* __restrict__ mel,
                                                  unsigned short* __restrict__ MelA) {
    long idx = (long)blockIdx.x * 256 + threadIdx.x;
    int elem = idx & 7;
    int lane = (idx >> 3) & 63;
    int kkm  = (int)((idx >> 9) % 3);
    int m    = (int)((idx / 1536) & 1);
    int t    = (int)(idx / 3072);
    int b    = m * 16 + (lane & 15);
    int km   = kkm * 32 + ((lane >> 4) & 3) * 8 + elem;
    float v = (km < CND) ? mel[((size_t)b * LEN + t) * CND + km] : (km == CND ? 1.f : 0.f);
    __hip_bfloat16 hb = __float2bfloat16(v);
    MelA[idx] = *(unsigned short*)&hb;
}

__global__ __launch_bounds__(256) void build_wfrag(const float* __restrict__ W,
                                                   unsigned short* __restrict__ Wf,
                                                   int K, int N) {
    int idx = blockIdx.x * 256 + threadIdx.x;
    if (idx >= K * N) return;
    int col = idx % N;
    int k   = idx / N;
    int nt = col >> 4, c = col & 15;
    int kf = k >> 5, k5 = k & 31;
    int lane = c + 16 * (k5 >> 3);
    int elem = k5 & 7;
    size_t dst = ((size_t)nt * (K >> 5) + kf) * 512 + (size_t)lane * 8 + elem;
    __hip_bfloat16 hb = __float2bfloat16(W[idx]);
    Wf[dst] = *(unsigned short*)&hb;
}

// ============================ persistent scan: consolidated batch-split + K-split ============================
// r18's scheme consolidated to 64 WGs x 512 thr (8 waves): each WG = 32 j-cols
// x 16 batches. Per-WG pull is still 32KB (GEMV needs full K), so HALVING the
// WG count HALVES total coherence traffic to 2MB/step (the lever that won in
// r17). Each wave pulls 4 frags (4KB) and computes partials for all 8 n-tiles
// (32 MFMAs, 8 chains of 4 -- more ILP than r18). Mel spread over waves 0-5.
// pex = [8 waves][8 tiles][256] = 64KB; gates sum 8 partials.
__device__ __forceinline__ int is_sent(unsigned long long q) {
    return ((unsigned)q == 0xFFFFFFFFu) || ((unsigned)(q >> 32) == 0xFFFFFFFFu);
}

__global__ __launch_bounds__(512, 1) void scan_persist(const unsigned short* __restrict__ Bf,
                                                       const unsigned short* __restrict__ MelA,
                                                       unsigned short* __restrict__ Af,
                                                       const float* __restrict__ tab1,
                                                       const float* __restrict__ tab2,
                                                       const float* __restrict__ tab3,
                                                       const int* __restrict__ xin) {
    __shared__ float pex[8][8][256];   // [wave][n-tile][lane*4+r] = 64 KB

    int tid = threadIdx.x;
    int wg  = blockIdx.x;
    int lane = tid & 63;
    int wv = tid >> 6;            // 0..7 = K-slice (frags wv*4..wv*4+3)
    int bh = wg >> 5;             // batch half (0: b0-15, 1: b16-31)
    int jg = wg & 31;             // j-slice: columns jg*32 .. jg*32+31

    // B-fragment base pointers for the 8 n-tiles (oct = jg*4 + (nt>>1), which = nt&1)
    const unsigned short* Bp0 = Bf + (((size_t)(jg * 4 + 0) * 2 + 0) * 35) * 512 + lane * 8;
    const unsigned short* Bp1 = Bf + (((size_t)(jg * 4 + 0) * 2 + 1) * 35) * 512 + lane * 8;
    const unsigned short* Bp2 = Bf + (((size_t)(jg * 4 + 1) * 2 + 0) * 35) * 512 + lane * 8;
    const unsigned short* Bp3 = Bf + (((size_t)(jg * 4 + 1) * 2 + 1) * 35) * 512 + lane * 8;
    const unsigned short* Bp4 = Bf + (((size_t)(jg * 4 + 2) * 2 + 0) * 35) * 512 + lane * 8;
    const unsigned short* Bp5 = Bf + (((size_t)(jg * 4 + 2) * 2 + 1) * 35) * 512 + lane * 8;
    const unsigned short* Bp6 = Bf + (((size_t)(jg * 4 + 3) * 2 + 0) * 35) * 512 + lane * 8;
    const unsigned short* Bp7 = Bf + (((size_t)(jg * 4 + 3) * 2 + 1) * 35) * 512 + lane * 8;

    // gate role: one (b, j) per thread
    int bl = tid >> 5, gjl = tid & 31;
    int gb = bh * 16 + bl;
    int gj = jg * 32 + gjl;
    float hreg = 0.f;
    size_t wbase = (size_t)((bh * 32 + (gj >> 5)) * 512 +
                            (bl + 16 * ((gj >> 3) & 3)) * 8 + (gj & 7));
    // gate read positions in pex (C layout: element (row=bl,col) at lane=(bl>>2)*16+col, r=bl&3)
    int p  = gjl >> 3, jo = gjl & 7;
    int nt_ur = p * 2, nt_e = p * 2 + 1;
    int ru = ((bl >> 2) * 16 + jo) * 4 + (bl & 3);          // col jo   (u / e1)
    int rr = ((bl >> 2) * 16 + 8 + jo) * 4 + (bl & 3);      // col 8+jo (r / e2)

#pragma unroll 1
    for (int t = 0; t < LEN; ++t) {
        // ---- table gathers (cached, hot; issued early, consumed late) ----
        int ci = xin[(gb * LEN + t) * 2];
        int fi = xin[(gb * LEN + t) * 2 + 1];
        int cn = xin[(gb * LEN + ((t + 1) & (LEN - 1))) * 2];
        float t1u = tab1[(size_t)ci * H3 + gj];
        float t2u = tab2[(size_t)fi * H3 + gj];
        float t3u = tab3[(size_t)cn * H3 + gj];
        float t1r = tab1[(size_t)ci * H3 + 1024 + gj];
        float t2r = tab2[(size_t)fi * H3 + 1024 + gj];
        float t3r = tab3[(size_t)cn * H3 + 1024 + gj];
        float t1e = tab1[(size_t)ci * H3 + 2048 + gj];
        float t2e = tab2[(size_t)fi * H3 + 2048 + gj];
        float t3e = tab3[(size_t)cn * H3 + 2048 + gj];

        // ---- pull this wave's 4 A-frags of Af[t] (own batch half) ----
        const unsigned long long* bp =
            (const unsigned long long*)(Af + (size_t)t * 32768 +
                                        (size_t)(bh * 32 + wv * 4) * 512) + lane * 2;
        unsigned long long q[8];
#pragma unroll
        for (int i = 0; i < 4; ++i) {
            q[2 * i]     = __hip_atomic_load(bp + i * 128,     __ATOMIC_RELAXED, __HIP_MEMORY_SCOPE_AGENT);
            q[2 * i + 1] = __hip_atomic_load(bp + i * 128 + 1, __ATOMIC_RELAXED, __HIP_MEMORY_SCOPE_AGENT);
        }
        for (;;) {
            int bad = 0;
#pragma unroll
            for (int i = 0; i < 8; ++i) bad |= is_sent(q[i]);
            if (!__any(bad)) break;
            __builtin_amdgcn_s_sleep(1);
#pragma unroll
            for (int i = 0; i < 4; ++i) {
                q[2 * i]     = __hip_atomic_load(bp + i * 128,     __ATOMIC_RELAXED, __HIP_MEMORY_SCOPE_AGENT);
                q[2 * i + 1] = __hip_atomic_load(bp + i * 128 + 1, __ATOMIC_RELAXED, __HIP_MEMORY_SCOPE_AGENT);
            }
        }

        // ---- partial K-sums: A from pull registers, all 8 n-tiles ----
        vf4 acc0 = {0.f, 0.f, 0.f, 0.f}, acc1 = {0.f, 0.f, 0.f, 0.f};
        vf4 acc2 = {0.f, 0.f, 0.f, 0.f}, acc3 = {0.f, 0.f, 0.f, 0.f};
        vf4 acc4 = {0.f, 0.f, 0.f, 0.f}, acc5 = {0.f, 0.f, 0.f, 0.f};
        vf4 acc6 = {0.f, 0.f, 0.f, 0.f}, acc7 = {0.f, 0.f, 0.f, 0.f};
#pragma unroll
        for (int i = 0; i < 4; ++i) {
            union { unsigned long long qq[2]; vbf8 v; } ua;
            ua.qq[0] = q[2 * i]; ua.qq[1] = q[2 * i + 1];
            vbf8 a = ua.v;
            int kk = wv * 4 + i;
            acc0 = __builtin_amdgcn_mfma_f32_16x16x32_bf16(a, *(const vbf8*)(Bp0 + kk * 512), acc0, 0, 0, 0);
            acc1 = __builtin_amdgcn_mfma_f32_16x16x32_bf16(a, *(const vbf8*)(Bp1 + kk * 512), acc1, 0, 0, 0);
            acc2 = __builtin_amdgcn_mfma_f32_16x16x32_bf16(a, *(const vbf8*)(Bp2 + kk * 512), acc2, 0, 0, 0);
            acc3 = __builtin_amdgcn_mfma_f32_16x16x32_bf16(a, *(const vbf8*)(Bp3 + kk * 512), acc3, 0, 0, 0);
            acc4 = __builtin_amdgcn_mfma_f32_16x16x32_bf16(a, *(const vbf8*)(Bp4 + kk * 512), acc4, 0, 0, 0);
            acc5 = __builtin_amdgcn_mfma_f32_16x16x32_bf16(a, *(const vbf8*)(Bp5 + kk * 512), acc5, 0, 0, 0);
            acc6 = __builtin_amdgcn_mfma_f32_16x16x32_bf16(a, *(const vbf8*)(Bp6 + kk * 512), acc6, 0, 0, 0);
            acc7 = __builtin_amdgcn_mfma_f32_16x16x32_bf16(a, *(const vbf8*)(Bp7 + kk * 512), acc7, 0, 0, 0);
        }
        if (wv < 6) {   // mel k-frag kq = wv>>1 on tile half (wv&1)
            int kq = wv >> 1;
            vbf8 am = *(const vbf8*)(MelA + (size_t)t * 3072 + (size_t)(bh * 3 + kq) * 512 + lane * 8);
            if ((wv & 1) == 0) {
                acc0 = __builtin_amdgcn_mfma_f32_16x16x32_bf16(am, *(const vbf8*)(Bp0 + (32 + kq) * 512), acc0, 0, 0, 0);
                acc1 = __builtin_amdgcn_mfma_f32_16x16x32_bf16(am, *(const vbf8*)(Bp1 + (32 + kq) * 512), acc1, 0, 0, 0);
                acc2 = __builtin_amdgcn_mfma_f32_16x16x32_bf16(am, *(const vbf8*)(Bp2 + (32 + kq) * 512), acc2, 0, 0, 0);
                acc3 = __builtin_amdgcn_mfma_f32_16x16x32_bf16(am, *(const vbf8*)(Bp3 + (32 + kq) * 512), acc3, 0, 0, 0);
            } else {
                acc4 = __builtin_amdgcn_mfma_f32_16x16x32_bf16(am, *(const vbf8*)(Bp4 + (32 + kq) * 512), acc4, 0, 0, 0);
                acc5 = __builtin_amdgcn_mfma_f32_16x16x32_bf16(am, *(const vbf8*)(Bp5 + (32 + kq) * 512), acc5, 0, 0, 0);
                acc6 = __builtin_amdgcn_mfma_f32_16x16x32_bf16(am, *(const vbf8*)(Bp6 + (32 + kq) * 512), acc6, 0, 0, 0);
                acc7 = __builtin_amdgcn_mfma_f32_16x16x32_bf16(am, *(const vbf8*)(Bp7 + (32 + kq) * 512), acc7, 0, 0, 0);
            }
        }

        // ---- write partials ----
        *(vf4*)&pex[wv][0][lane * 4] = acc0;
        *(vf4*)&pex[wv][1][lane * 4] = acc1;
        *(vf4*)&pex[wv][2][lane * 4] = acc2;
        *(vf4*)&pex[wv][3][lane * 4] = acc3;
        *(vf4*)&pex[wv][4][lane * 4] = acc4;
        *(vf4*)&pex[wv][5][lane * 4] = acc5;
        *(vf4*)&pex[wv][6][lane * 4] = acc6;
        *(vf4*)&pex[wv][7][lane * 4] = acc7;
        __syncthreads();

        // ---- gates: sum 8 partials per value + tables ----
        float gu  = ((pex[0][nt_ur][ru] + pex[1][nt_ur][ru]) + (pex[2][nt_ur][ru] + pex[3][nt_ur][ru]))
                  + ((pex[4][nt_ur][ru] + pex[5][nt_ur][ru]) + (pex[6][nt_ur][ru] + pex[7][nt_ur][ru]))
                  + t1u + t2u + t3u;
        float gr  = ((pex[0][nt_ur][rr] + pex[1][nt_ur][rr]) + (pex[2][nt_ur][rr] + pex[3][nt_ur][rr]))
                  + ((pex[4][nt_ur][rr] + pex[5][nt_ur][rr]) + (pex[6][nt_ur][rr] + pex[7][nt_ur][rr]))
                  + t1r + t2r + t3r;
        float e1  = ((pex[0][nt_e][ru] + pex[1][nt_e][ru]) + (pex[2][nt_e][ru] + pex[3][nt_e][ru]))
                  + ((pex[4][nt_e][ru] + pex[5][nt_e][ru]) + (pex[6][nt_e][ru] + pex[7][nt_e][ru]));
        float ge2 = ((pex[0][nt_e][rr] + pex[1][nt_e][rr]) + (pex[2][nt_e][rr] + pex[3][nt_e][rr]))
                  + ((pex[4][nt_e][rr] + pex[5][nt_e][rr]) + (pex[6][nt_e][rr] + pex[7][nt_e][rr]))
                  + t1e + t2e + t3e;
        float u  = 1.f / (1.f + expf(-gu));
        float r_ = 1.f / (1.f + expf(-gr));
        float e  = tanhf(r_ * e1 + ge2);
        hreg = u * hreg + (1.f - u) * e;

        // ---- fire-and-forget packed h store (pair via shfl) ----
        __hip_bfloat16 hb = __float2bfloat16(hreg);
        int myv = (int)(*(unsigned short*)&hb);
        int nbv = __shfl_xor(myv, 1);
        if ((tid & 1) == 0) {
            unsigned int pk = ((unsigned)myv & 0xffffu) | ((unsigned)nbv << 16);
            __hip_atomic_store((unsigned int*)(Af + (size_t)(t + 1) * 32768 + wbase), pk,
                               __ATOMIC_RELAXED, __HIP_MEMORY_SCOPE_AGENT);
        }
        __syncthreads();   // protect pex reuse next iteration
    }
}

// ============================ MFMA output MLPs (r12 verbatim) ============================
__global__ __launch_bounds__(512) void out_mlp_mfma(
        const unsigned short* __restrict__ Af,
        const unsigned short* __restrict__ W1f, const float* __restrict__ O1b,
        const unsigned short* __restrict__ W2f, const float* __restrict__ O2b,
        const unsigned short* __restrict__ W3f, const float* __restrict__ O3b,
        const unsigned short* __restrict__ W4f, const float* __restrict__ O4b,
        float* __restrict__ out) {
    __shared__ __align__(16) unsigned short Zc[2 * 24 * 512];   // 48 KB
    __shared__ __align__(16) unsigned short Zf[2 * 8 * 512];    // 16 KB

    int tid = threadIdx.x;
    int lane = tid & 63;
    int wv = tid >> 6;
    int m = wv >> 2;
    int q = wv & 3;
    int l = blockIdx.x;
    int c16 = lane & 15;
    int rowq = lane >> 4;

    const unsigned short* Abase = Af + (size_t)(l + 1) * 32768 +
                                  (size_t)(m * 32) * 512 + (size_t)lane * 8;

    {
        vf4 acc[12];
#pragma unroll
        for (int i = 0; i < 12; ++i) acc[i] = (vf4){0.f, 0.f, 0.f, 0.f};
        for (int kk = 0; kk < 24; ++kk) {
            vbf8 a = *(const vbf8*)(Abase + kk * 512);
#pragma unroll
            for (int i = 0; i < 12; ++i) {
                int nt = q * 12 + i;
                vbf8 b = *(const vbf8*)(W1f + ((size_t)nt * 24 + kk) * 512 + lane * 8);
                acc[i] = __builtin_amdgcn_mfma_f32_16x16x32_bf16(a, b, acc[i], 0, 0, 0);
            }
        }
#pragma unroll
        for (int i = 0; i < 12; ++i) {
            int nt = q * 12 + i;
            int col = nt * 16 + c16;
            float bias = O1b[col];
#pragma unroll
            for (int r = 0; r < 4; ++r) {
                float v = fmaxf(acc[i][r] + bias, 0.f);
                __hip_bfloat16 hb = __float2bfloat16(v);
                int my = (int)*(unsigned short*)&hb;
                int nb = __shfl_xor(my, 1);
                if ((lane & 1) == 0) {
                    unsigned pk = ((unsigned)my & 0xffffu) | ((unsigned)nb << 16);
                    int row = rowq * 4 + r;
                    int kk2 = col >> 5, k5 = col & 31;
                    int lp = row + 16 * (k5 >> 3);
                    int ep = k5 & 7;
                    *(unsigned*)&Zc[(size_t)(m * 24 + kk2) * 512 + lp * 8 + ep] = pk;
                }
            }
        }
    }
    __syncthreads();

    {
        vf4 acc[4];
#pragma unroll
        for (int i = 0; i < 4; ++i) acc[i] = (vf4){0.f, 0.f, 0.f, 0.f};
        for (int kk = 0; kk < 24; ++kk) {
            vbf8 a = *(const vbf8*)(Zc + (size_t)(m * 24 + kk) * 512 + lane * 8);
#pragma unroll
            for (int i = 0; i < 4; ++i) {
                int nt = q * 4 + i;
                vbf8 b = *(const vbf8*)(W2f + ((size_t)nt * 24 + kk) * 512 + lane * 8);
                acc[i] = __builtin_amdgcn_mfma_f32_16x16x32_bf16(a, b, acc[i], 0, 0, 0);
            }
        }
#pragma unroll
        for (int i = 0; i < 4; ++i) {
            int nt = q * 4 + i;
            int col = nt * 16 + c16;
            float bias = O2b[col];
#pragma unroll
            for (int r = 0; r < 4; ++r) {
                int nn = m * 16 + rowq * 4 + r;
                out[((size_t)nn * 1024 + l) * 256 + col] = acc[i][r] + bias;
            }
        }
    }

    {
        vf4 acc[4];
#pragma unroll
        for (int i = 0; i < 4; ++i) acc[i] = (vf4){0.f, 0.f, 0.f, 0.f};
        for (int kf = 0; kf < 8; ++kf) {
            vbf8 a = *(const vbf8*)(Abase + (24 + kf) * 512);
#pragma unroll
            for (int i = 0; i < 4; ++i) {
                int nt = q * 4 + i;
                vbf8 b = *(const vbf8*)(W3f + ((size_t)nt * 8 + kf) * 512 + lane * 8);
                acc[i] = __builtin_amdgcn_mfma_f32_16x16x32_bf16(a, b, acc[i], 0, 0, 0);
            }
        }
#pragma unroll
        for (int i = 0; i < 4; ++i) {
            int nt = q * 4 + i;
            int col = nt * 16 + c16;
            float bias = O3b[col];
#pragma unroll
            for (int r = 0; r < 4; ++r) {
                float v = fmaxf(acc[i][r] + bias, 0.f);
                __hip_bfloat16 hb = __float2bfloat16(v);
                int my = (int)*(unsigned short*)&hb;
                int nb = __shfl_xor(my, 1);
                if ((lane & 1) == 0) {
                    unsigned pk = ((unsigned)my & 0xffffu) | ((unsigned)nb << 16);
                    int row = rowq * 4 + r;
                    int kk2 = col >> 5, k5 = col & 31;
                    int lp = row + 16 * (k5 >> 3);
                    int ep = k5 & 7;
                    *(unsigned*)&Zf[(size_t)(m * 8 + kk2) * 512 + lp * 8 + ep] = pk;
                }
            }
        }
    }
    __syncthreads();

    {
        vf4 acc[4];
#pragma unroll
        for (int i = 0; i < 4; ++i) acc[i] = (vf4){0.f, 0.f, 0.f, 0.f};
        for (int kf = 0; kf < 8; ++kf) {
            vbf8 a = *(const vbf8*)(Zf + (size_t)(m * 8 + kf) * 512 + lane * 8);
#pragma unroll
            for (int i = 0; i < 4; ++i) {
                int nt = q * 4 + i;
                vbf8 b = *(const vbf8*)(W4f + ((size_t)nt * 8 + kf) * 512 + lane * 8);
                acc[i] = __builtin_amdgcn_mfma_f32_16x16x32_bf16(a, b, acc[i], 0, 0, 0);
            }
        }
#pragma unroll
        for (int i = 0; i < 4; ++i) {
            int nt = q * 4 + i;
            int col = nt * 16 + c16;
            float bias = O4b[col];
#pragma unroll
            for (int r = 0; r < 4; ++r) {
                int nn = m * 16 + rowq * 4 + r;
                out[FOFS + ((size_t)nn * 1024 + l) * 256 + col] = acc[i][r] + bias;
            }
        }
    }
}

// ============================ launch ============================
extern "C" void kernel_launch(void* const* d_in, const int* in_sizes, int n_in,
                              void* d_out, int out_size, void* d_ws, size_t ws_size,
                              hipStream_t stream) {
    const int*   x    = (const int*)d_in[0];
    const float* mel  = (const float*)d_in[1];
    const float* Rw   = (const float*)d_in[2];
    const float* Rb   = (const float*)d_in[3];
    const float* IW   = (const float*)d_in[4];
    const float* Ib   = (const float*)d_in[5];
    const float* O1w  = (const float*)d_in[6];
    const float* O1b  = (const float*)d_in[7];
    const float* O2w  = (const float*)d_in[8];
    const float* O2b  = (const float*)d_in[9];
    const float* O3w  = (const float*)d_in[10];
    const float* O3b  = (const float*)d_in[11];
    const float* O4w  = (const float*)d_in[12];
    const float* O4b  = (const float*)d_in[13];
    const float* cemb = (const float*)d_in[14];
    const float* femb = (const float*)d_in[15];
    char* wsb = (char*)d_ws;
    float* out = (float*)d_out;

    float* tab1 = (float*)(wsb + TAB1_B);
    float* tab2 = (float*)(wsb + TAB2_B);
    float* tab3 = (float*)(wsb + TAB3_B);
    unsigned short* Bf   = (unsigned short*)(wsb + BF_B);
    unsigned short* MelA = (unsigned short*)(wsb + MELA_B);
    unsigned short* Af   = (unsigned short*)(wsb + AF_B);
    unsigned short* W1f  = (unsigned short*)(wsb + W1F_B);
    unsigned short* W2f  = (unsigned short*)(wsb + W2F_B);
    unsigned short* W3f  = (unsigned short*)(wsb + W3F_B);
    unsigned short* W4f  = (unsigned short*)(wsb + W4F_B);

    make_tables<<<9216, 256, 0, stream>>>(IW, Ib, cemb, femb, tab1, tab2, tab3);
    hipMemsetAsync((void*)Bf, 0, 4587520ull * 2, stream);
    build_bfrag2<<<13440, 256, 0, stream>>>(Rw, IW, Rb, Bf);
    build_melA<<<12288, 256, 0, stream>>>(mel, MelA);
    build_wfrag<<<2304, 256, 0, stream>>>(O1w, W1f, 768, 768);
    build_wfrag<<<768,  256, 0, stream>>>(O2w, W2f, 768, 256);
    build_wfrag<<<256,  256, 0, stream>>>(O3w, W3f, 256, 256);
    build_wfrag<<<256,  256, 0, stream>>>(O4w, W4f, 256, 256);
    hipMemsetAsync((void*)Af, 0xFF, 33587200ull * 2, stream);   // sentinel-seed all slots
    hipMemsetAsync((void*)Af, 0, 65536, stream);                // h0 = 0 (slot 0 readable)

    scan_persist<<<NWG, NTHR, 0, stream>>>(Bf, MelA, Af, tab1, tab2, tab3, x);

    out_mlp_mfma<<<1024, 512, 0, stream>>>(Af, W1f, O1b, W2f, O2b, W3f, O3b, W4f, O4b, out);
}

// Round 20
// 2700.629 us; speedup vs baseline: 1.2508x; 1.2508x over previous
//
#include <hip/hip_runtime.h>
#include <hip/hip_bf16.h>
#include <math.h>

typedef __attribute__((ext_vector_type(4))) float vf4;
typedef __attribute__((ext_vector_type(8))) short vbf8;
typedef __attribute__((ext_vector_type(8))) unsigned short vus8;

#define NWG   128
#define NTHR  256
#define LEN   1024
#define H3    3072
#define CND   80
#define EMBD  128

// ---- ws byte offsets ----
#define TAB1_B  0ull
#define TAB2_B  (TAB1_B + 786432ull*4)
#define TAB3_B  (TAB2_B + 786432ull*4)
#define BF_B    (TAB3_B + 786432ull*4)            // bfrag: 128oct*2which*35frag*512 bf16
#define MELA_B  (BF_B   + 4587520ull*2)           // melA : 1024t*2m*3frag*512 bf16
#define AF_B    (MELA_B + 3145728ull*2)           // Afrag: 1025t*64frag*512 bf16
#define CNT_B   (AF_B   + 33587200ull*2)          // (unused)
#define W1F_B   (CNT_B + 4096ull)                 // O1w frags
#define W2F_B   (W1F_B + 1179648ull)
#define W3F_B   (W2F_B + 393216ull)
#define W4F_B   (W3F_B + 131072ull)
#define FOFS    8388608ull                        // flogits offset in d_out

// ============================ prep kernels (verbatim) ============================

__global__ __launch_bounds__(256) void make_tables(const float* __restrict__ IW,
                                                   const float* __restrict__ Ib,
                                                   const float* __restrict__ cemb,
                                                   const float* __restrict__ femb,
                                                   float* __restrict__ tab1,
                                                   float* __restrict__ tab2,
                                                   float* __restrict__ tab3) {
    int blk = blockIdx.x;
    int table = blk / 3072;
    int rem = blk % 3072;
    int row = rem / 12;
    int cc = rem % 12;
    int col = cc * 256 + threadIdx.x;
    int ofs = CND + table * EMBD;
    const float* emb = (table == 1) ? femb : cemb;
    float acc = 0.f;
    for (int k = 0; k < EMBD; ++k)
        acc += emb[row * EMBD + k] * IW[(size_t)(ofs + k) * H3 + col];
    if (table == 0) acc += Ib[col];
    if (table == 2 && ((col & 1023) < 768)) acc = 0.f;
    float* dst = (table == 0) ? tab1 : (table == 1 ? tab2 : tab3);
    dst[(size_t)row * H3 + col] = acc;
}

__global__ __launch_bounds__(256) void build_bfrag2(const float* __restrict__ Rw,
                                                    const float* __restrict__ IW,
                                                    const float* __restrict__ Rb,
                                                    unsigned short* __restrict__ Bf) {
    int idx = blockIdx.x * 256 + threadIdx.x;     // k*3072 + col, k in 0..1119
    int col = idx % 3072;
    int k   = idx / 3072;
    float v;
    if (k < 1024)       v = Rw[(size_t)k * H3 + col];
    else if (k < 1104)  v = IW[(size_t)(k - 1024) * H3 + col];
    else if (k == 1104) v = Rb[col];
    else return;

    int g  = col >> 10;
    int j  = col & 1023;
    int oct = j >> 3, jo = j & 7;
    int which, c;
    if (g < 2)      { which = 0; c = g * 8 + jo; }
    else {
        which = 1;
        if (k < 1024 || k == 1104) c = jo;
        else                        c = 8 + jo;
    }
    int kk = k >> 5, r5 = k & 31;
    int lane = (r5 >> 3) * 16 + c;
    int elem = r5 & 7;
    size_t dst = (((size_t)oct * 2 + which) * 35 + kk) * 512 + lane * 8 + elem;
    __hip_bfloat16 hb = __float2bfloat16(v);
    Bf[dst] = *(unsigned short*)&hb;
}

__global__ __launch_bounds__(256) void build_melA(const float* __restrict__ mel,
                                                  unsigned short* __restrict__ MelA) {
    long idx = (long)blockIdx.x * 256 + threadIdx.x;
    int elem = idx & 7;
    int lane = (idx >> 3) & 63;
    int kkm  = (int)((idx >> 9) % 3);
    int m    = (int)((idx / 1536) & 1);
    int t    = (int)(idx / 3072);
    int b    = m * 16 + (lane & 15);
    int km   = kkm * 32 + ((lane >> 4) & 3) * 8 + elem;
    float v = (km < CND) ? mel[((size_t)b * LEN + t) * CND + km] : (km == CND ? 1.f : 0.f);
    __hip_bfloat16 hb = __float2bfloat16(v);
    MelA[idx] = *(unsigned short*)&hb;
}

__global__ __launch_bounds__(256) void build_wfrag(const float* __restrict__ W,
                                                   unsigned short* __restrict__ Wf,
                                                   int K, int N) {
    int idx = blockIdx.x * 256 + threadIdx.x;
    if (idx >= K * N) return;
    int col = idx % N;
    int k   = idx / N;
    int nt = col >> 4, c = col & 15;
    int kf = k >> 5, k5 = k & 31;
    int lane = c + 16 * (k5 >> 3);
    int elem = k5 & 7;
    size_t dst = ((size_t)nt * (K >> 5) + kf) * 512 + (size_t)lane * 8 + elem;
    __hip_bfloat16 hb = __float2bfloat16(W[idx]);
    Wf[dst] = *(unsigned short*)&hb;
}

// ============================ persistent scan: batch-split + K-split dataflow (r18, best) ============================
__device__ __forceinline__ int is_sent(unsigned long long q) {
    return ((unsigned)q == 0xFFFFFFFFu) || ((unsigned)(q >> 32) == 0xFFFFFFFFu);
}

__global__ __launch_bounds__(256, 1) void scan_persist(const unsigned short* __restrict__ Bf,
                                                       const unsigned short* __restrict__ MelA,
                                                       unsigned short* __restrict__ Af,
                                                       const float* __restrict__ tab1,
                                                       const float* __restrict__ tab2,
                                                       const float* __restrict__ tab3,
                                                       const int* __restrict__ xin) {
    __shared__ float pex[4][4][256];   // [wave][n-tile][lane*4+r] = 16 KB

    int tid = threadIdx.x;
    int wg  = blockIdx.x;
    int lane = tid & 63;
    int wv = tid >> 6;            // 0..3 = K-slice (frags wv*8..wv*8+7)
    int bh = wg >> 6;             // batch half (0: b0-15, 1: b16-31)
    int jg = wg & 63;             // j-slice: columns jg*16 .. jg*16+15

    // B-fragment base pointers for the 4 n-tiles (p=nt>>1, which=nt&1)
    const unsigned short* Bp0 = Bf + (((size_t)(jg * 2 + 0) * 2 + 0) * 35) * 512 + lane * 8;
    const unsigned short* Bp1 = Bf + (((size_t)(jg * 2 + 0) * 2 + 1) * 35) * 512 + lane * 8;
    const unsigned short* Bp2 = Bf + (((size_t)(jg * 2 + 1) * 2 + 0) * 35) * 512 + lane * 8;
    const unsigned short* Bp3 = Bf + (((size_t)(jg * 2 + 1) * 2 + 1) * 35) * 512 + lane * 8;

    // gate role: one (b, j) per thread
    int bl = tid >> 4, gjl = tid & 15;
    int gb = bh * 16 + bl;
    int gj = jg * 16 + gjl;
    float hreg = 0.f;
    size_t wbase = (size_t)((bh * 32 + (gj >> 5)) * 512 +
                            (bl + 16 * ((gj >> 3) & 3)) * 8 + (gj & 7));
    // gate read positions in pex: value at (row=bl, col=c) = [lane=(bl>>2)*16+c][r=bl&3]
    int p  = gjl >> 3, jo = gjl & 7;
    int nt_ur = p * 2, nt_e = p * 2 + 1;
    int ru = ((bl >> 2) * 16 + jo) * 4 + (bl & 3);          // col jo   (u / e1)
    int rr = ((bl >> 2) * 16 + 8 + jo) * 4 + (bl & 3);      // col 8+jo (r / e2)

#pragma unroll 1
    for (int t = 0; t < LEN; ++t) {
        // ---- table gathers (cached, hot; issued early, consumed late) ----
        int ci = xin[(gb * LEN + t) * 2];
        int fi = xin[(gb * LEN + t) * 2 + 1];
        int cn = xin[(gb * LEN + ((t + 1) & (LEN - 1))) * 2];
        float t1u = tab1[(size_t)ci * H3 + gj];
        float t2u = tab2[(size_t)fi * H3 + gj];
        float t3u = tab3[(size_t)cn * H3 + gj];
        float t1r = tab1[(size_t)ci * H3 + 1024 + gj];
        float t2r = tab2[(size_t)fi * H3 + 1024 + gj];
        float t3r = tab3[(size_t)cn * H3 + 1024 + gj];
        float t1e = tab1[(size_t)ci * H3 + 2048 + gj];
        float t2e = tab2[(size_t)fi * H3 + 2048 + gj];
        float t3e = tab3[(size_t)cn * H3 + 2048 + gj];

        // ---- pull this wave's 8 A-frags of Af[t] (own batch half) ----
        const unsigned long long* bp =
            (const unsigned long long*)(Af + (size_t)t * 32768 +
                                        (size_t)(bh * 32 + wv * 8) * 512) + lane * 2;
        unsigned long long q[16];
#pragma unroll
        for (int i = 0; i < 8; ++i) {
            q[2 * i]     = __hip_atomic_load(bp + i * 128,     __ATOMIC_RELAXED, __HIP_MEMORY_SCOPE_AGENT);
            q[2 * i + 1] = __hip_atomic_load(bp + i * 128 + 1, __ATOMIC_RELAXED, __HIP_MEMORY_SCOPE_AGENT);
        }
        for (;;) {
            int bad = 0;
#pragma unroll
            for (int i = 0; i < 16; ++i) bad |= is_sent(q[i]);
            if (!__any(bad)) break;
            __builtin_amdgcn_s_sleep(1);
#pragma unroll
            for (int i = 0; i < 8; ++i) {
                q[2 * i]     = __hip_atomic_load(bp + i * 128,     __ATOMIC_RELAXED, __HIP_MEMORY_SCOPE_AGENT);
                q[2 * i + 1] = __hip_atomic_load(bp + i * 128 + 1, __ATOMIC_RELAXED, __HIP_MEMORY_SCOPE_AGENT);
            }
        }

        // ---- partial K-sums: A from pull registers, all 4 n-tiles ----
        vf4 acc0 = {0.f, 0.f, 0.f, 0.f}, acc1 = {0.f, 0.f, 0.f, 0.f};
        vf4 acc2 = {0.f, 0.f, 0.f, 0.f}, acc3 = {0.f, 0.f, 0.f, 0.f};
#pragma unroll
        for (int i = 0; i < 8; ++i) {
            union { unsigned long long qq[2]; vbf8 v; } ua;
            ua.qq[0] = q[2 * i]; ua.qq[1] = q[2 * i + 1];
            vbf8 a = ua.v;
            int kk = wv * 8 + i;
            acc0 = __builtin_amdgcn_mfma_f32_16x16x32_bf16(a, *(const vbf8*)(Bp0 + kk * 512), acc0, 0, 0, 0);
            acc1 = __builtin_amdgcn_mfma_f32_16x16x32_bf16(a, *(const vbf8*)(Bp1 + kk * 512), acc1, 0, 0, 0);
            acc2 = __builtin_amdgcn_mfma_f32_16x16x32_bf16(a, *(const vbf8*)(Bp2 + kk * 512), acc2, 0, 0, 0);
            acc3 = __builtin_amdgcn_mfma_f32_16x16x32_bf16(a, *(const vbf8*)(Bp3 + kk * 512), acc3, 0, 0, 0);
        }
        if (wv < 3) {   // mel k-fragment kq = wv, all 4 tiles
            vbf8 am = *(const vbf8*)(MelA + (size_t)t * 3072 + (size_t)(bh * 3 + wv) * 512 + lane * 8);
            acc0 = __builtin_amdgcn_mfma_f32_16x16x32_bf16(am, *(const vbf8*)(Bp0 + (32 + wv) * 512), acc0, 0, 0, 0);
            acc1 = __builtin_amdgcn_mfma_f32_16x16x32_bf16(am, *(const vbf8*)(Bp1 + (32 + wv) * 512), acc1, 0, 0, 0);
            acc2 = __builtin_amdgcn_mfma_f32_16x16x32_bf16(am, *(const vbf8*)(Bp2 + (32 + wv) * 512), acc2, 0, 0, 0);
            acc3 = __builtin_amdgcn_mfma_f32_16x16x32_bf16(am, *(const vbf8*)(Bp3 + (32 + wv) * 512), acc3, 0, 0, 0);
        }

        // ---- write partials ----
        *(vf4*)&pex[wv][0][lane * 4] = acc0;
        *(vf4*)&pex[wv][1][lane * 4] = acc1;
        *(vf4*)&pex[wv][2][lane * 4] = acc2;
        *(vf4*)&pex[wv][3][lane * 4] = acc3;
        __syncthreads();

        // ---- gates: sum 4 partials per value + tables ----
        float gu  = pex[0][nt_ur][ru] + pex[1][nt_ur][ru] + pex[2][nt_ur][ru] + pex[3][nt_ur][ru]
                  + t1u + t2u + t3u;
        float gr  = pex[0][nt_ur][rr] + pex[1][nt_ur][rr] + pex[2][nt_ur][rr] + pex[3][nt_ur][rr]
                  + t1r + t2r + t3r;
        float e1  = pex[0][nt_e][ru] + pex[1][nt_e][ru] + pex[2][nt_e][ru] + pex[3][nt_e][ru];
        float ge2 = pex[0][nt_e][rr] + pex[1][nt_e][rr] + pex[2][nt_e][rr] + pex[3][nt_e][rr]
                  + t1e + t2e + t3e;
        float u  = 1.f / (1.f + expf(-gu));
        float r_ = 1.f / (1.f + expf(-gr));
        float e  = tanhf(r_ * e1 + ge2);
        hreg = u * hreg + (1.f - u) * e;

        // ---- fire-and-forget packed h store (pair via shfl) ----
        __hip_bfloat16 hb = __float2bfloat16(hreg);
        int myv = (int)(*(unsigned short*)&hb);
        int nbv = __shfl_xor(myv, 1);
        if ((tid & 1) == 0) {
            unsigned int pk = ((unsigned)myv & 0xffffu) | ((unsigned)nbv << 16);
            __hip_atomic_store((unsigned int*)(Af + (size_t)(t + 1) * 32768 + wbase), pk,
                               __ATOMIC_RELAXED, __HIP_MEMORY_SCOPE_AGENT);
        }
        __syncthreads();   // protect pex reuse next iteration
    }
}

// ============================ MFMA output MLPs (r12 verbatim) ============================
__global__ __launch_bounds__(512) void out_mlp_mfma(
        const unsigned short* __restrict__ Af,
        const unsigned short* __restrict__ W1f, const float* __restrict__ O1b,
        const unsigned short* __restrict__ W2f, const float* __restrict__ O2b,
        const unsigned short* __restrict__ W3f, const float* __restrict__ O3b,
        const unsigned short* __restrict__ W4f, const float* __restrict__ O4b,
        float* __restrict__ out) {
    __shared__ __align__(16) unsigned short Zc[2 * 24 * 512];   // 48 KB
    __shared__ __align__(16) unsigned short Zf[2 * 8 * 512];    // 16 KB

    int tid = threadIdx.x;
    int lane = tid & 63;
    int wv = tid >> 6;
    int m = wv >> 2;
    int q = wv & 3;
    int l = blockIdx.x;
    int c16 = lane & 15;
    int rowq = lane >> 4;

    const unsigned short* Abase = Af + (size_t)(l + 1) * 32768 +
                                  (size_t)(m * 32) * 512 + (size_t)lane * 8;

    {
        vf4 acc[12];
#pragma unroll
        for (int i = 0; i < 12; ++i) acc[i] = (vf4){0.f, 0.f, 0.f, 0.f};
        for (int kk = 0; kk < 24; ++kk) {
            vbf8 a = *(const vbf8*)(Abase + kk * 512);
#pragma unroll
            for (int i = 0; i < 12; ++i) {
                int nt = q * 12 + i;
                vbf8 b = *(const vbf8*)(W1f + ((size_t)nt * 24 + kk) * 512 + lane * 8);
                acc[i] = __builtin_amdgcn_mfma_f32_16x16x32_bf16(a, b, acc[i], 0, 0, 0);
            }
        }
#pragma unroll
        for (int i = 0; i < 12; ++i) {
            int nt = q * 12 + i;
            int col = nt * 16 + c16;
            float bias = O1b[col];
#pragma unroll
            for (int r = 0; r < 4; ++r) {
                float v = fmaxf(acc[i][r] + bias, 0.f);
                __hip_bfloat16 hb = __float2bfloat16(v);
                int my = (int)*(unsigned short*)&hb;
                int nb = __shfl_xor(my, 1);
                if ((lane & 1) == 0) {
                    unsigned pk = ((unsigned)my & 0xffffu) | ((unsigned)nb << 16);
                    int row = rowq * 4 + r;
                    int kk2 = col >> 5, k5 = col & 31;
                    int lp = row + 16 * (k5 >> 3);
                    int ep = k5 & 7;
                    *(unsigned*)&Zc[(size_t)(m * 24 + kk2) * 512 + lp * 8 + ep] = pk;
                }
            }
        }
    }
    __syncthreads();

    {
        vf4 acc[4];
#pragma unroll
        for (int i = 0; i < 4; ++i) acc[i] = (vf4){0.f, 0.f, 0.f, 0.f};
        for (int kk = 0; kk < 24; ++kk) {
            vbf8 a = *(const vbf8*)(Zc + (size_t)(m * 24 + kk) * 512 + lane * 8);
#pragma unroll
            for (int i = 0; i < 4; ++i) {
                int nt = q * 4 + i;
                vbf8 b = *(const vbf8*)(W2f + ((size_t)nt * 24 + kk) * 512 + lane * 8);
                acc[i] = __builtin_amdgcn_mfma_f32_16x16x32_bf16(a, b, acc[i], 0, 0, 0);
            }
        }
#pragma unroll
        for (int i = 0; i < 4; ++i) {
            int nt = q * 4 + i;
            int col = nt * 16 + c16;
            float bias = O2b[col];
#pragma unroll
            for (int r = 0; r < 4; ++r) {
                int nn = m * 16 + rowq * 4 + r;
                out[((size_t)nn * 1024 + l) * 256 + col] = acc[i][r] + bias;
            }
        }
    }

    {
        vf4 acc[4];
#pragma unroll
        for (int i = 0; i < 4; ++i) acc[i] = (vf4){0.f, 0.f, 0.f, 0.f};
        for (int kf = 0; kf < 8; ++kf) {
            vbf8 a = *(const vbf8*)(Abase + (24 + kf) * 512);
#pragma unroll
            for (int i = 0; i < 4; ++i) {
                int nt = q * 4 + i;
                vbf8 b = *(const vbf8*)(W3f + ((size_t)nt * 8 + kf) * 512 + lane * 8);
                acc[i] = __builtin_amdgcn_mfma_f32_16x16x32_bf16(a, b, acc[i], 0, 0, 0);
            }
        }
#pragma unroll
        for (int i = 0; i < 4; ++i) {
            int nt = q * 4 + i;
            int col = nt * 16 + c16;
            float bias = O3b[col];
#pragma unroll
            for (int r = 0; r < 4; ++r) {
                float v = fmaxf(acc[i][r] + bias, 0.f);
                __hip_bfloat16 hb = __float2bfloat16(v);
                int my = (int)*(unsigned short*)&hb;
                int nb = __shfl_xor(my, 1);
                if ((lane & 1) == 0) {
                    unsigned pk = ((unsigned)my & 0xffffu) | ((unsigned)nb << 16);
                    int row = rowq * 4 + r;
                    int kk2 = col >> 5, k5 = col & 31;
                    int lp = row + 16 * (k5 >> 3);
                    int ep = k5 & 7;
                    *(unsigned*)&Zf[(size_t)(m * 8 + kk2) * 512 + lp * 8 + ep] = pk;
                }
            }
        }
    }
    __syncthreads();

    {
        vf4 acc[4];
#pragma unroll
        for (int i = 0; i < 4; ++i) acc[i] = (vf4){0.f, 0.f, 0.f, 0.f};
        for (int kf = 0; kf < 8; ++kf) {
            vbf8 a = *(const vbf8*)(Zf + (size_t)(m * 8 + kf) * 512 + lane * 8);
#pragma unroll
            for (int i = 0; i < 4; ++i) {
                int nt = q * 4 + i;
                vbf8 b = *(const vbf8*)(W4f + ((size_t)nt * 8 + kf) * 512 + lane * 8);
                acc[i] = __builtin_amdgcn_mfma_f32_16x16x32_bf16(a, b, acc[i], 0, 0, 0);
            }
        }
#pragma unroll
        for (int i = 0; i < 4; ++i) {
            int nt = q * 4 + i;
            int col = nt * 16 + c16;
            float bias = O4b[col];
#pragma unroll
            for (int r = 0; r < 4; ++r) {
                int nn = m * 16 + rowq * 4 + r;
                out[FOFS + ((size_t)nn * 1024 + l) * 256 + col] = acc[i][r] + bias;
            }
        }
    }
}

// ============================ launch ============================
extern "C" void kernel_launch(void* const* d_in, const int* in_sizes, int n_in,
                              void* d_out, int out_size, void* d_ws, size_t ws_size,
                              hipStream_t stream) {
    const int*   x    = (const int*)d_in[0];
    const float* mel  = (const float*)d_in[1];
    const float* Rw   = (const float*)d_in[2];
    const float* Rb   = (const float*)d_in[3];
    const float* IW   = (const float*)d_in[4];
    const float* Ib   = (const float*)d_in[5];
    const float* O1w  = (const float*)d_in[6];
    const float* O1b  = (const float*)d_in[7];
    const float* O2w  = (const float*)d_in[8];
    const float* O2b  = (const float*)d_in[9];
    const float* O3w  = (const float*)d_in[10];
    const float* O3b  = (const float*)d_in[11];
    const float* O4w  = (const float*)d_in[12];
    const float* O4b  = (const float*)d_in[13];
    const float* cemb = (const float*)d_in[14];
    const float* femb = (const float*)d_in[15];
    char* wsb = (char*)d_ws;
    float* out = (float*)d_out;

    float* tab1 = (float*)(wsb + TAB1_B);
    float* tab2 = (float*)(wsb + TAB2_B);
    float* tab3 = (float*)(wsb + TAB3_B);
    unsigned short* Bf   = (unsigned short*)(wsb + BF_B);
    unsigned short* MelA = (unsigned short*)(wsb + MELA_B);
    unsigned short* Af   = (unsigned short*)(wsb + AF_B);
    unsigned short* W1f  = (unsigned short*)(wsb + W1F_B);
    unsigned short* W2f  = (unsigned short*)(wsb + W2F_B);
    unsigned short* W3f  = (unsigned short*)(wsb + W3F_B);
    unsigned short* W4f  = (unsigned short*)(wsb + W4F_B);

    make_tables<<<9216, 256, 0, stream>>>(IW, Ib, cemb, femb, tab1, tab2, tab3);
    hipMemsetAsync((void*)Bf, 0, 4587520ull * 2, stream);
    build_bfrag2<<<13440, 256, 0, stream>>>(Rw, IW, Rb, Bf);
    build_melA<<<12288, 256, 0, stream>>>(mel, MelA);
    build_wfrag<<<2304, 256, 0, stream>>>(O1w, W1f, 768, 768);
    build_wfrag<<<768,  256, 0, stream>>>(O2w, W2f, 768, 256);
    build_wfrag<<<256,  256, 0, stream>>>(O3w, W3f, 256, 256);
    build_wfrag<<<256,  256, 0, stream>>>(O4w, W4f, 256, 256);
    hipMemsetAsync((void*)Af, 0xFF, 33587200ull * 2, stream);   // sentinel-seed all slots
    hipMemsetAsync((void*)Af, 0, 65536, stream);                // h0 = 0 (slot 0 readable)

    scan_persist<<<NWG, NTHR, 0, stream>>>(Bf, MelA, Af, tab1, tab2, tab3, x);

    out_mlp_mfma<<<1024, 512, 0, stream>>>(Af, W1f, O1b, W2f, O2b, W3f, O3b, W4f, O4b, out);
}